// Round 8
// baseline (103.346 us; speedup 1.0000x reference)
//
#include <hip/hip_runtime.h>
#include <hip/hip_bf16.h>
#include <math.h>

#define BATCH 2
#define CCH 64
#define WW 64
#define RR 32
#define HWD 4096
#define LOG2E 1.4426950408889634f

typedef __attribute__((ext_vector_type(8))) short bf16x8;
typedef __attribute__((ext_vector_type(4))) float f32x4;
typedef __attribute__((ext_vector_type(2))) unsigned int uint2v;
typedef __attribute__((ext_vector_type(4))) unsigned int uint4v;

__device__ __forceinline__ ushort f2b(float x) {
    __hip_bfloat16 h = __float2bfloat16(x);
    return *reinterpret_cast<ushort*>(&h);
}
__device__ __forceinline__ uint pk2(float a, float b) {
    return (uint)f2b(a) | ((uint)f2b(b) << 16);
}

// ---------------------------------------------------------------------------
// prep: 1x1 convs. kind 0 -> theta*log2e [sb][4096][32] bf16 (+pre, +qadd)
//       kind 1 -> phi   [sb][4096][32] bf16 (+kadd)
//       kind 2 -> gT2   [sb][34][4096] bf16 (rows 32=ones, 33=col)
// ---------------------------------------------------------------------------
__global__ __launch_bounds__(256) void prep_kernel(
    const float* __restrict__ left, const float* __restrict__ right,
    const float* __restrict__ pre_l, const float* __restrict__ pre_r,
    const float* __restrict__ query_l, const float* __restrict__ key_l,
    const float* __restrict__ query_r, const float* __restrict__ key_r,
    const float* __restrict__ w_theta, const float* __restrict__ b_theta,
    const float* __restrict__ w_phi, const float* __restrict__ b_phi,
    const float* __restrict__ w_g, const float* __restrict__ b_g,
    ushort* __restrict__ thetaB, ushort* __restrict__ phiB,
    ushort* __restrict__ gT2)
{
    __shared__ float w_s[64][RR];
    __shared__ float wx_s[RR];
    __shared__ float bias_s[RR];
    int tid = threadIdx.x;
    int kind = blockIdx.x >> 6;

    if (kind == 0) {
        for (int i = tid; i < 65 * RR; i += 256) {
            int r = i / 65, c = i % 65;
            if (c < 64) w_s[c][r] = w_theta[i]; else wx_s[r] = w_theta[i];
        }
        if (tid < RR) bias_s[tid] = b_theta[tid];
    } else {
        const float* wsrc = (kind == 1) ? w_phi : w_g;
        const float* bsrc = (kind == 1) ? b_phi : b_g;
        for (int i = tid; i < 64 * RR; i += 256) {
            int r = i >> 6, c = i & 63;
            w_s[c][r] = wsrc[i];
        }
        if (tid < RR) bias_s[tid] = bsrc[tid];
    }
    __syncthreads();

    int t = (blockIdx.x & 63) * 256 + tid;   // 0..16383
    int sb = t >> 12;
    int side = sb >> 1;
    int b = sb & 1;
    int p = t & 4095;

    const float* X;
    if (kind == 0) X = side ? right : left;   // xq
    else           X = side ? left  : right;  // xk

    float acc[RR];
    #pragma unroll
    for (int r = 0; r < RR; ++r) acc[r] = bias_s[r];

    const float* xp = X + (size_t)b * CCH * HWD + p;
    for (int c = 0; c < CCH; ++c) {
        float xv = xp[(size_t)c * HWD];
        #pragma unroll
        for (int r = 0; r < RR; ++r) acc[r] += w_s[c][r] * xv;
    }

    if (kind == 0) {
        const float* pre  = side ? pre_r   : pre_l;
        const float* qadd = side ? query_r : query_l;
        float pv = pre[(size_t)b * HWD + p] * (1.0f / 64.0f);
        uint4v u4[4];
        #pragma unroll
        for (int r = 0; r < RR; r += 2) {
            float v0 = (acc[r]   + wx_s[r]   * pv + qadd[((size_t)b * RR + r)   * HWD + p]) * LOG2E;
            float v1 = (acc[r+1] + wx_s[r+1] * pv + qadd[((size_t)b * RR + r+1) * HWD + p]) * LOG2E;
            u4[r >> 3][(r >> 1) & 3] = pk2(v0, v1);
        }
        uint4v* dst = (uint4v*)(thetaB + (size_t)t * RR);
        #pragma unroll
        for (int i = 0; i < 4; ++i) dst[i] = u4[i];
    } else if (kind == 1) {
        const float* kadd = side ? key_l : key_r;
        uint4v u4[4];
        #pragma unroll
        for (int r = 0; r < RR; r += 2) {
            float v0 = acc[r]   + kadd[((size_t)b * RR + r)   * HWD + p];
            float v1 = acc[r+1] + kadd[((size_t)b * RR + r+1) * HWD + p];
            u4[r >> 3][(r >> 1) & 3] = pk2(v0, v1);
        }
        uint4v* dst = (uint4v*)(phiB + (size_t)t * RR);
        #pragma unroll
        for (int i = 0; i < 4; ++i) dst[i] = u4[i];
    } else {
        ushort* gdst = gT2 + (size_t)sb * 34 * HWD + p;
        #pragma unroll
        for (int r = 0; r < RR; ++r) gdst[(size_t)r * HWD] = f2b(acc[r]);
        gdst[(size_t)32 * HWD] = 0x3F80;               // 1.0 bf16
        gdst[(size_t)33 * HWD] = f2b((float)(p & 63)); // col
    }
}

// ---------------------------------------------------------------------------
// attn: block = (sb, q-pair of 32); 8 waves = key splits of 512.
// P (32 KB, single-buffer) overlaid by the entire epilogue:
//   accbuf[4][2][34][17] (18.5 KB, tree-reduced: waves 4-7 += into 0-3)
//   a_s[32][36] at +18560 (4.6 KB)
// up-conv reads W_up/b_up from global; y written straight to yB (f32x4/thread).
// ---------------------------------------------------------------------------
__global__ __launch_bounds__(512, 8) void attn_kernel(
    const ushort* __restrict__ thetaB, const ushort* __restrict__ phiB,
    const ushort* __restrict__ gT2,
    const float* __restrict__ w_up, const float* __restrict__ b_up,
    float* __restrict__ yB, float* __restrict__ part,
    float* __restrict__ d_out)
{
    __shared__ __attribute__((aligned(16))) char smem[32768];
    auto P      = reinterpret_cast<ushort(*)[2][16][64]>(smem);  // [8][2][16][64] = 32 KB
    auto accbuf = reinterpret_cast<float(*)[2][34][17]>(smem);   // [4][2][34][17] = 18.5 KB
    float* a_s  = (float*)(smem + 18560);                        // [32][36] = 4.6 KB

    int tid = threadIdx.x;
    int w = tid >> 6, l = tid & 63;
    int ql = l & 15, kgrp = l >> 4;
    int sb = blockIdx.x >> 7;              // 512 blocks: sb x 128 q-pairs
    int qpair = blockIdx.x & 127;
    int q0 = qpair * 32;

    const ushort* thb = thetaB + (size_t)sb * HWD * RR;
    const ushort* phb = phiB + (size_t)sb * HWD * RR;
    const ushort* gtb = gT2 + (size_t)sb * 34 * HWD;

    bf16x8 bf0 = *(const bf16x8*)(thb + (size_t)(q0 + ql) * RR + kgrp * 8);
    bf16x8 bf1 = *(const bf16x8*)(thb + (size_t)(q0 + 16 + ql) * RR + kgrp * 8);

    const f32x4 zf = {0.f, 0.f, 0.f, 0.f};
    f32x4 acc00 = zf, acc01 = zf, acc02 = zf;
    f32x4 acc10 = zf, acc11 = zf, acc12 = zf;

    int swz = (ql & 7) << 4;
    int grow2 = (ql == 0) ? 32 : 33;
    char* p0base = (char*)&P[w][0][ql][0];
    char* p1base = (char*)&P[w][1][ql][0];

    for (int kb = 0; kb < 8; ++kb) {
        int kbase = w * 512 + kb * 64;

        // hoist g loads: overlap with QK + exp phase
        const ushort* gp = gtb + kbase + kgrp * 8;
        bf16x8 g00 = *(const bf16x8*)(gp + (size_t)ql * HWD);
        bf16x8 g10 = *(const bf16x8*)(gp + (size_t)(16 + ql) * HWD);
        bf16x8 g20 = *(const bf16x8*)(gp + (size_t)grow2 * HWD);
        bf16x8 g01 = *(const bf16x8*)(gp + (size_t)ql * HWD + 32);
        bf16x8 g11 = *(const bf16x8*)(gp + (size_t)(16 + ql) * HWD + 32);
        bf16x8 g21 = *(const bf16x8*)(gp + (size_t)grow2 * HWD + 32);

        #pragma unroll
        for (int j = 0; j < 4; ++j) {
            bf16x8 aphi = *(const bf16x8*)(phb + (size_t)(kbase + 16 * j + ql) * RR + kgrp * 8);
            f32x4 s0 = __builtin_amdgcn_mfma_f32_16x16x32_bf16(aphi, bf0, zf, 0, 0, 0);
            f32x4 s1 = __builtin_amdgcn_mfma_f32_16x16x32_bf16(aphi, bf1, zf, 0, 0, 0);
            int co = (32 * j + 8 * kgrp) ^ swz;
            uint2v w0, w1;
            w0[0] = pk2(exp2f(s0[0]), exp2f(s0[1]));
            w0[1] = pk2(exp2f(s0[2]), exp2f(s0[3]));
            w1[0] = pk2(exp2f(s1[0]), exp2f(s1[1]));
            w1[1] = pk2(exp2f(s1[2]), exp2f(s1[3]));
            *(uint2v*)(p0base + co) = w0;
            *(uint2v*)(p1base + co) = w1;
        }

        #pragma unroll
        for (int kc = 0; kc < 2; ++kc) {
            int co = (64 * kc + 16 * kgrp) ^ swz;
            bf16x8 pb0 = *(const bf16x8*)(p0base + co);
            bf16x8 pb1 = *(const bf16x8*)(p1base + co);
            bf16x8 ga = kc ? g01 : g00;
            bf16x8 gb = kc ? g11 : g10;
            bf16x8 gc = kc ? g21 : g20;
            acc00 = __builtin_amdgcn_mfma_f32_16x16x32_bf16(ga, pb0, acc00, 0, 0, 0);
            acc01 = __builtin_amdgcn_mfma_f32_16x16x32_bf16(gb, pb0, acc01, 0, 0, 0);
            acc02 = __builtin_amdgcn_mfma_f32_16x16x32_bf16(gc, pb0, acc02, 0, 0, 0);
            acc10 = __builtin_amdgcn_mfma_f32_16x16x32_bf16(ga, pb1, acc10, 0, 0, 0);
            acc11 = __builtin_amdgcn_mfma_f32_16x16x32_bf16(gb, pb1, acc11, 0, 0, 0);
            acc12 = __builtin_amdgcn_mfma_f32_16x16x32_bf16(gc, pb1, acc12, 0, 0, 0);
        }
    }

    // P region dead from here; accbuf/a_s overlay it
    __syncthreads();

    if (w < 4) {
        #pragma unroll
        for (int r = 0; r < 4; ++r) {
            accbuf[w][0][4 * kgrp + r][ql] = acc00[r];
            accbuf[w][0][16 + 4 * kgrp + r][ql] = acc01[r];
            accbuf[w][1][4 * kgrp + r][ql] = acc10[r];
            accbuf[w][1][16 + 4 * kgrp + r][ql] = acc11[r];
        }
        if (kgrp == 0) {
            accbuf[w][0][32][ql] = acc02[0];
            accbuf[w][0][33][ql] = acc02[1];
            accbuf[w][1][32][ql] = acc12[0];
            accbuf[w][1][33][ql] = acc12[1];
        }
    }
    __syncthreads();

    if (w >= 4) {
        int wd = w - 4;
        #pragma unroll
        for (int r = 0; r < 4; ++r) {
            accbuf[wd][0][4 * kgrp + r][ql] += acc00[r];
            accbuf[wd][0][16 + 4 * kgrp + r][ql] += acc01[r];
            accbuf[wd][1][4 * kgrp + r][ql] += acc10[r];
            accbuf[wd][1][16 + 4 * kgrp + r][ql] += acc11[r];
        }
        if (kgrp == 0) {
            accbuf[wd][0][32][ql] += acc02[0];
            accbuf[wd][0][33][ql] += acc02[1];
            accbuf[wd][1][32][ql] += acc12[0];
            accbuf[wd][1][33][ql] += acc12[1];
        }
    }
    __syncthreads();

    // reduce 4 buffers; a -> a_s; index row 33 -> d_out
    for (int i = tid; i < 2 * 34 * 16; i += 512) {
        int t = i / 544, rem = i % 544;
        int rp = rem >> 4, qq = rem & 15;
        float v = 0.f, s = 0.f;
        #pragma unroll
        for (int ww = 0; ww < 4; ++ww) {
            v += accbuf[ww][t][rp][qq];
            s += accbuf[ww][t][32][qq];
        }
        int Q = q0 + t * 16 + qq;
        if (rp < 32) {
            a_s[(t * 16 + qq) * 36 + rp] = v / s;
        } else if (rp == 33) {
            d_out[(size_t)2 * BATCH * CCH * HWD + (size_t)sb * HWD + Q] =
                (float)(Q & 63) - v / s;
        }
    }
    __syncthreads();

    // fused up-conv: y[o][q] = b_up[o] + sum_r wup[o][r] * a[q][r]
    // thread (o, qg) owns q = qg*4..qg*4+3 -> one f32x4 store to yB
    {
        int o = tid >> 3, qg = tid & 7;
        float bu = b_up[o];
        float yv[4] = {bu, bu, bu, bu};
        const float* wrow = w_up + o * RR;
        #pragma unroll
        for (int r4 = 0; r4 < 8; ++r4) {
            f32x4 wv = *(const f32x4*)(wrow + r4 * 4);
            #pragma unroll
            for (int j = 0; j < 4; ++j) {
                f32x4 av = *(const f32x4*)(a_s + (qg * 4 + j) * 36 + r4 * 4);
                yv[j] += av[0] * wv[0] + av[1] * wv[1] + av[2] * wv[2] + av[3] * wv[3];
            }
        }
        float s1 = yv[0] + yv[1] + yv[2] + yv[3];
        float s2 = yv[0]*yv[0] + yv[1]*yv[1] + yv[2]*yv[2] + yv[3]*yv[3];
        #pragma unroll
        for (int m = 1; m < 8; m <<= 1) {
            s1 += __shfl_xor(s1, m, 8);
            s2 += __shfl_xor(s2, m, 8);
        }
        if (qg == 0) {
            part[((size_t)blockIdx.x * 64 + o) * 2]     = s1;
            part[((size_t)blockIdx.x * 64 + o) * 2 + 1] = s2;
        }
        f32x4 y4 = {yv[0], yv[1], yv[2], yv[3]};
        *(f32x4*)(yB + (((size_t)sb * 64 + o) << 12) + q0 + qg * 4) = y4;
    }
}

// ---------------------------------------------------------------------------
// apply: block = (side,b,o). Finalize BN scale/shift from part, then
// out = x + y*scale + shift  (pure streaming f32x4)
// ---------------------------------------------------------------------------
__global__ __launch_bounds__(256) void apply_kernel(
    const float* __restrict__ left, const float* __restrict__ right,
    const float* __restrict__ yB, const float* __restrict__ part,
    const float* __restrict__ gamma, const float* __restrict__ beta,
    float* __restrict__ d_out)
{
    __shared__ float r1[4], r2[4], ssc[2];
    int bid = blockIdx.x;                  // 256: side|b|o
    int side = bid >> 7, b = (bid >> 6) & 1, o = bid & 63;
    int tid = threadIdx.x;
    int w = tid >> 6, l = tid & 63;

    // finalize: sum this side's 256 block-partials for channel o
    const float* pp = part + (((size_t)(side * 256 + tid)) * 64 + o) * 2;
    float s1 = pp[0], s2 = pp[1];
    #pragma unroll
    for (int m = 1; m < 64; m <<= 1) {
        s1 += __shfl_xor(s1, m);
        s2 += __shfl_xor(s2, m);
    }
    if (l == 0) { r1[w] = s1; r2[w] = s2; }
    __syncthreads();
    if (tid == 0) {
        float S1 = r1[0] + r1[1] + r1[2] + r1[3];
        float S2 = r2[0] + r2[1] + r2[2] + r2[3];
        float n = (float)(BATCH * HWD);
        float mean = S1 / n;
        float var = S2 / n - mean * mean;
        float scale = gamma[o] / sqrtf(var + 1e-5f);
        ssc[0] = scale;
        ssc[1] = beta[o] - mean * scale;
    }
    __syncthreads();
    float scale = ssc[0], shift = ssc[1];

    const float* x = side ? right : left;
    const f32x4* yp = (const f32x4*)(yB + (((size_t)(side * 2 + b) * 64 + o) << 12));
    const f32x4* xp = (const f32x4*)(x + (((size_t)b * 64 + o) << 12));
    f32x4* op = (f32x4*)(d_out + (size_t)side * (BATCH * CCH * HWD)
                         + (((size_t)b * 64 + o) << 12));

    #pragma unroll
    for (int i = 0; i < 4; ++i) {
        int idx = tid + i * 256;
        f32x4 yv = yp[idx];
        f32x4 xv = xp[idx];
        f32x4 ov;
        ov[0] = xv[0] + yv[0] * scale + shift;
        ov[1] = xv[1] + yv[1] * scale + shift;
        ov[2] = xv[2] + yv[2] * scale + shift;
        ov[3] = xv[3] + yv[3] * scale + shift;
        op[idx] = ov;
    }
}

extern "C" void kernel_launch(void* const* d_in, const int* in_sizes, int n_in,
                              void* d_out, int out_size, void* d_ws, size_t ws_size,
                              hipStream_t stream)
{
    const float* left    = (const float*)d_in[0];
    const float* right   = (const float*)d_in[1];
    const float* pre_l   = (const float*)d_in[2];
    const float* pre_r   = (const float*)d_in[3];
    const float* query_l = (const float*)d_in[4];
    const float* key_l   = (const float*)d_in[5];
    const float* query_r = (const float*)d_in[6];
    const float* key_r   = (const float*)d_in[7];
    const float* w_theta = (const float*)d_in[8];
    const float* b_theta = (const float*)d_in[9];
    const float* w_phi   = (const float*)d_in[10];
    const float* b_phi   = (const float*)d_in[11];
    const float* w_g     = (const float*)d_in[12];
    const float* b_g     = (const float*)d_in[13];
    const float* w_up    = (const float*)d_in[14];
    const float* b_up    = (const float*)d_in[15];
    const float* gamma   = (const float*)d_in[16];
    const float* beta    = (const float*)d_in[17];

    char* ws = (char*)d_ws;
    ushort* thetaB  = (ushort*)ws;                       // 1,048,576
    ushort* phiB    = (ushort*)(ws + 1048576);           // 1,048,576
    ushort* gT2     = (ushort*)(ws + 2097152);           // 1,114,112
    float*  yB      = (float*)(ws + 3211264);            // 4,194,304
    float*  part    = (float*)(ws + 7405568);            // 262,144  (ends 7,667,712)

    prep_kernel<<<192, 256, 0, stream>>>(left, right, pre_l, pre_r,
                                         query_l, key_l, query_r, key_r,
                                         w_theta, b_theta, w_phi, b_phi,
                                         w_g, b_g, thetaB, phiB, gT2);
    attn_kernel<<<512, 512, 0, stream>>>(thetaB, phiB, gT2, w_up, b_up,
                                         yB, part, (float*)d_out);
    apply_kernel<<<256, 256, 0, stream>>>(left, right, yB, part,
                                          gamma, beta, (float*)d_out);
}

// Round 9
// 63.147 us; speedup vs baseline: 1.6366x; 1.6366x over previous
//
#include <hip/hip_runtime.h>
#include <hip/hip_bf16.h>
#include <math.h>

#define BATCH 2
#define CCH 64
#define WW 64
#define RR 32
#define HWD 4096
#define LOG2E 1.4426950408889634f

typedef __attribute__((ext_vector_type(8))) short bf16x8;
typedef __attribute__((ext_vector_type(4))) float f32x4;
typedef __attribute__((ext_vector_type(2))) unsigned int uint2v;
typedef __attribute__((ext_vector_type(4))) unsigned int uint4v;

__device__ __forceinline__ ushort f2b(float x) {
    __hip_bfloat16 h = __float2bfloat16(x);
    return *reinterpret_cast<ushort*>(&h);
}
__device__ __forceinline__ uint pk2(float a, float b) {
    return (uint)f2b(a) | ((uint)f2b(b) << 16);
}

// ---------------------------------------------------------------------------
// prep: 1x1 convs. kind 0 -> theta*log2e [sb][4096][32] bf16 (+pre, +qadd)
//       kind 1 -> phi   [sb][4096][32] bf16 (+kadd)
//       kind 2 -> gT2   [sb][34][4096] bf16 (rows 32=ones, 33=col)
// ---------------------------------------------------------------------------
__global__ __launch_bounds__(256) void prep_kernel(
    const float* __restrict__ left, const float* __restrict__ right,
    const float* __restrict__ pre_l, const float* __restrict__ pre_r,
    const float* __restrict__ query_l, const float* __restrict__ key_l,
    const float* __restrict__ query_r, const float* __restrict__ key_r,
    const float* __restrict__ w_theta, const float* __restrict__ b_theta,
    const float* __restrict__ w_phi, const float* __restrict__ b_phi,
    const float* __restrict__ w_g, const float* __restrict__ b_g,
    ushort* __restrict__ thetaB, ushort* __restrict__ phiB,
    ushort* __restrict__ gT2)
{
    __shared__ float w_s[64][RR];
    __shared__ float wx_s[RR];
    __shared__ float bias_s[RR];
    int tid = threadIdx.x;
    int kind = blockIdx.x >> 6;

    if (kind == 0) {
        for (int i = tid; i < 65 * RR; i += 256) {
            int r = i / 65, c = i % 65;
            if (c < 64) w_s[c][r] = w_theta[i]; else wx_s[r] = w_theta[i];
        }
        if (tid < RR) bias_s[tid] = b_theta[tid];
    } else {
        const float* wsrc = (kind == 1) ? w_phi : w_g;
        const float* bsrc = (kind == 1) ? b_phi : b_g;
        for (int i = tid; i < 64 * RR; i += 256) {
            int r = i >> 6, c = i & 63;
            w_s[c][r] = wsrc[i];
        }
        if (tid < RR) bias_s[tid] = bsrc[tid];
    }
    __syncthreads();

    int t = (blockIdx.x & 63) * 256 + tid;   // 0..16383
    int sb = t >> 12;
    int side = sb >> 1;
    int b = sb & 1;
    int p = t & 4095;

    const float* X;
    if (kind == 0) X = side ? right : left;   // xq
    else           X = side ? left  : right;  // xk

    float acc[RR];
    #pragma unroll
    for (int r = 0; r < RR; ++r) acc[r] = bias_s[r];

    const float* xp = X + (size_t)b * CCH * HWD + p;
    for (int c = 0; c < CCH; ++c) {
        float xv = xp[(size_t)c * HWD];
        #pragma unroll
        for (int r = 0; r < RR; ++r) acc[r] += w_s[c][r] * xv;
    }

    if (kind == 0) {
        const float* pre  = side ? pre_r   : pre_l;
        const float* qadd = side ? query_r : query_l;
        float pv = pre[(size_t)b * HWD + p] * (1.0f / 64.0f);
        uint4v u4[4];
        #pragma unroll
        for (int r = 0; r < RR; r += 2) {
            float v0 = (acc[r]   + wx_s[r]   * pv + qadd[((size_t)b * RR + r)   * HWD + p]) * LOG2E;
            float v1 = (acc[r+1] + wx_s[r+1] * pv + qadd[((size_t)b * RR + r+1) * HWD + p]) * LOG2E;
            u4[r >> 3][(r >> 1) & 3] = pk2(v0, v1);
        }
        uint4v* dst = (uint4v*)(thetaB + (size_t)t * RR);
        #pragma unroll
        for (int i = 0; i < 4; ++i) dst[i] = u4[i];
    } else if (kind == 1) {
        const float* kadd = side ? key_l : key_r;
        uint4v u4[4];
        #pragma unroll
        for (int r = 0; r < RR; r += 2) {
            float v0 = acc[r]   + kadd[((size_t)b * RR + r)   * HWD + p];
            float v1 = acc[r+1] + kadd[((size_t)b * RR + r+1) * HWD + p];
            u4[r >> 3][(r >> 1) & 3] = pk2(v0, v1);
        }
        uint4v* dst = (uint4v*)(phiB + (size_t)t * RR);
        #pragma unroll
        for (int i = 0; i < 4; ++i) dst[i] = u4[i];
    } else {
        ushort* gdst = gT2 + (size_t)sb * 34 * HWD + p;
        #pragma unroll
        for (int r = 0; r < RR; ++r) gdst[(size_t)r * HWD] = f2b(acc[r]);
        gdst[(size_t)32 * HWD] = 0x3F80;               // 1.0 bf16
        gdst[(size_t)33 * HWD] = f2b((float)(p & 63)); // col
    }
}

// ---------------------------------------------------------------------------
// attn: block = (sb, q-pair of 32); 8 waves = key splits of 512.
// P (32 KB, single-buffer) overlaid by the entire epilogue:
//   accbuf[4][2][34][17] (18.5 KB, tree-reduced: waves 4-7 += into 0-3)
//   a_s[32][36] at +18560 (4.6 KB)
// launch_bounds (512,4): ~60 VGPR codegen -> 4 blocks/CU (LDS allows 5).
// ---------------------------------------------------------------------------
__global__ __launch_bounds__(512, 4) void attn_kernel(
    const ushort* __restrict__ thetaB, const ushort* __restrict__ phiB,
    const ushort* __restrict__ gT2,
    const float* __restrict__ w_up, const float* __restrict__ b_up,
    float* __restrict__ yB, float* __restrict__ part,
    float* __restrict__ d_out)
{
    __shared__ __attribute__((aligned(16))) char smem[32768];
    auto P      = reinterpret_cast<ushort(*)[2][16][64]>(smem);  // [8][2][16][64] = 32 KB
    auto accbuf = reinterpret_cast<float(*)[2][34][17]>(smem);   // [4][2][34][17] = 18.5 KB
    float* a_s  = (float*)(smem + 18560);                        // [32][36] = 4.6 KB

    int tid = threadIdx.x;
    int w = tid >> 6, l = tid & 63;
    int ql = l & 15, kgrp = l >> 4;
    int sb = blockIdx.x >> 7;              // 512 blocks: sb x 128 q-pairs
    int qpair = blockIdx.x & 127;
    int q0 = qpair * 32;

    const ushort* thb = thetaB + (size_t)sb * HWD * RR;
    const ushort* phb = phiB + (size_t)sb * HWD * RR;
    const ushort* gtb = gT2 + (size_t)sb * 34 * HWD;

    bf16x8 bf0 = *(const bf16x8*)(thb + (size_t)(q0 + ql) * RR + kgrp * 8);
    bf16x8 bf1 = *(const bf16x8*)(thb + (size_t)(q0 + 16 + ql) * RR + kgrp * 8);

    const f32x4 zf = {0.f, 0.f, 0.f, 0.f};
    f32x4 acc00 = zf, acc01 = zf, acc02 = zf;
    f32x4 acc10 = zf, acc11 = zf, acc12 = zf;

    int swz = (ql & 7) << 4;
    int grow2 = (ql == 0) ? 32 : 33;
    char* p0base = (char*)&P[w][0][ql][0];
    char* p1base = (char*)&P[w][1][ql][0];

    for (int kb = 0; kb < 8; ++kb) {
        int kbase = w * 512 + kb * 64;

        // hoist g loads: overlap with QK + exp phase
        const ushort* gp = gtb + kbase + kgrp * 8;
        bf16x8 g00 = *(const bf16x8*)(gp + (size_t)ql * HWD);
        bf16x8 g10 = *(const bf16x8*)(gp + (size_t)(16 + ql) * HWD);
        bf16x8 g20 = *(const bf16x8*)(gp + (size_t)grow2 * HWD);
        bf16x8 g01 = *(const bf16x8*)(gp + (size_t)ql * HWD + 32);
        bf16x8 g11 = *(const bf16x8*)(gp + (size_t)(16 + ql) * HWD + 32);
        bf16x8 g21 = *(const bf16x8*)(gp + (size_t)grow2 * HWD + 32);

        #pragma unroll
        for (int j = 0; j < 4; ++j) {
            bf16x8 aphi = *(const bf16x8*)(phb + (size_t)(kbase + 16 * j + ql) * RR + kgrp * 8);
            f32x4 s0 = __builtin_amdgcn_mfma_f32_16x16x32_bf16(aphi, bf0, zf, 0, 0, 0);
            f32x4 s1 = __builtin_amdgcn_mfma_f32_16x16x32_bf16(aphi, bf1, zf, 0, 0, 0);
            int co = (32 * j + 8 * kgrp) ^ swz;
            uint2v w0, w1;
            w0[0] = pk2(exp2f(s0[0]), exp2f(s0[1]));
            w0[1] = pk2(exp2f(s0[2]), exp2f(s0[3]));
            w1[0] = pk2(exp2f(s1[0]), exp2f(s1[1]));
            w1[1] = pk2(exp2f(s1[2]), exp2f(s1[3]));
            *(uint2v*)(p0base + co) = w0;
            *(uint2v*)(p1base + co) = w1;
        }

        #pragma unroll
        for (int kc = 0; kc < 2; ++kc) {
            int co = (64 * kc + 16 * kgrp) ^ swz;
            bf16x8 pb0 = *(const bf16x8*)(p0base + co);
            bf16x8 pb1 = *(const bf16x8*)(p1base + co);
            bf16x8 ga = kc ? g01 : g00;
            bf16x8 gb = kc ? g11 : g10;
            bf16x8 gc = kc ? g21 : g20;
            acc00 = __builtin_amdgcn_mfma_f32_16x16x32_bf16(ga, pb0, acc00, 0, 0, 0);
            acc01 = __builtin_amdgcn_mfma_f32_16x16x32_bf16(gb, pb0, acc01, 0, 0, 0);
            acc02 = __builtin_amdgcn_mfma_f32_16x16x32_bf16(gc, pb0, acc02, 0, 0, 0);
            acc10 = __builtin_amdgcn_mfma_f32_16x16x32_bf16(ga, pb1, acc10, 0, 0, 0);
            acc11 = __builtin_amdgcn_mfma_f32_16x16x32_bf16(gb, pb1, acc11, 0, 0, 0);
            acc12 = __builtin_amdgcn_mfma_f32_16x16x32_bf16(gc, pb1, acc12, 0, 0, 0);
        }
    }

    // P region dead from here; accbuf/a_s overlay it
    __syncthreads();

    if (w < 4) {
        #pragma unroll
        for (int r = 0; r < 4; ++r) {
            accbuf[w][0][4 * kgrp + r][ql] = acc00[r];
            accbuf[w][0][16 + 4 * kgrp + r][ql] = acc01[r];
            accbuf[w][1][4 * kgrp + r][ql] = acc10[r];
            accbuf[w][1][16 + 4 * kgrp + r][ql] = acc11[r];
        }
        if (kgrp == 0) {
            accbuf[w][0][32][ql] = acc02[0];
            accbuf[w][0][33][ql] = acc02[1];
            accbuf[w][1][32][ql] = acc12[0];
            accbuf[w][1][33][ql] = acc12[1];
        }
    }
    __syncthreads();

    if (w >= 4) {
        int wd = w - 4;
        #pragma unroll
        for (int r = 0; r < 4; ++r) {
            accbuf[wd][0][4 * kgrp + r][ql] += acc00[r];
            accbuf[wd][0][16 + 4 * kgrp + r][ql] += acc01[r];
            accbuf[wd][1][4 * kgrp + r][ql] += acc10[r];
            accbuf[wd][1][16 + 4 * kgrp + r][ql] += acc11[r];
        }
        if (kgrp == 0) {
            accbuf[wd][0][32][ql] += acc02[0];
            accbuf[wd][0][33][ql] += acc02[1];
            accbuf[wd][1][32][ql] += acc12[0];
            accbuf[wd][1][33][ql] += acc12[1];
        }
    }
    __syncthreads();

    // reduce 4 buffers; a -> a_s; index row 33 -> d_out
    for (int i = tid; i < 2 * 34 * 16; i += 512) {
        int t = i / 544, rem = i % 544;
        int rp = rem >> 4, qq = rem & 15;
        float v = 0.f, s = 0.f;
        #pragma unroll
        for (int ww = 0; ww < 4; ++ww) {
            v += accbuf[ww][t][rp][qq];
            s += accbuf[ww][t][32][qq];
        }
        int Q = q0 + t * 16 + qq;
        if (rp < 32) {
            a_s[(t * 16 + qq) * 36 + rp] = v / s;
        } else if (rp == 33) {
            d_out[(size_t)2 * BATCH * CCH * HWD + (size_t)sb * HWD + Q] =
                (float)(Q & 63) - v / s;
        }
    }
    __syncthreads();

    // fused up-conv: y[o][q] = b_up[o] + sum_r wup[o][r] * a[q][r]
    // thread (o, qg) owns q = qg*4..qg*4+3 -> one f32x4 store to yB
    {
        int o = tid >> 3, qg = tid & 7;
        float bu = b_up[o];
        float yv[4] = {bu, bu, bu, bu};
        const float* wrow = w_up + o * RR;
        #pragma unroll
        for (int r4 = 0; r4 < 8; ++r4) {
            f32x4 wv = *(const f32x4*)(wrow + r4 * 4);
            #pragma unroll
            for (int j = 0; j < 4; ++j) {
                f32x4 av = *(const f32x4*)(a_s + (qg * 4 + j) * 36 + r4 * 4);
                yv[j] += av[0] * wv[0] + av[1] * wv[1] + av[2] * wv[2] + av[3] * wv[3];
            }
        }
        float s1 = yv[0] + yv[1] + yv[2] + yv[3];
        float s2 = yv[0]*yv[0] + yv[1]*yv[1] + yv[2]*yv[2] + yv[3]*yv[3];
        #pragma unroll
        for (int m = 1; m < 8; m <<= 1) {
            s1 += __shfl_xor(s1, m, 8);
            s2 += __shfl_xor(s2, m, 8);
        }
        if (qg == 0) {
            part[((size_t)blockIdx.x * 64 + o) * 2]     = s1;
            part[((size_t)blockIdx.x * 64 + o) * 2 + 1] = s2;
        }
        f32x4 y4 = {yv[0], yv[1], yv[2], yv[3]};
        *(f32x4*)(yB + (((size_t)sb * 64 + o) << 12) + q0 + qg * 4) = y4;
    }
}

// ---------------------------------------------------------------------------
// apply: block = (side,b,o). Finalize BN scale/shift from part, then
// out = x + y*scale + shift  (pure streaming f32x4)
// ---------------------------------------------------------------------------
__global__ __launch_bounds__(256) void apply_kernel(
    const float* __restrict__ left, const float* __restrict__ right,
    const float* __restrict__ yB, const float* __restrict__ part,
    const float* __restrict__ gamma, const float* __restrict__ beta,
    float* __restrict__ d_out)
{
    __shared__ float r1[4], r2[4], ssc[2];
    int bid = blockIdx.x;                  // 256: side|b|o
    int side = bid >> 7, b = (bid >> 6) & 1, o = bid & 63;
    int tid = threadIdx.x;
    int w = tid >> 6, l = tid & 63;

    // finalize: sum this side's 256 block-partials for channel o
    const float* pp = part + (((size_t)(side * 256 + tid)) * 64 + o) * 2;
    float s1 = pp[0], s2 = pp[1];
    #pragma unroll
    for (int m = 1; m < 64; m <<= 1) {
        s1 += __shfl_xor(s1, m);
        s2 += __shfl_xor(s2, m);
    }
    if (l == 0) { r1[w] = s1; r2[w] = s2; }
    __syncthreads();
    if (tid == 0) {
        float S1 = r1[0] + r1[1] + r1[2] + r1[3];
        float S2 = r2[0] + r2[1] + r2[2] + r2[3];
        float n = (float)(BATCH * HWD);
        float mean = S1 / n;
        float var = S2 / n - mean * mean;
        float scale = gamma[o] / sqrtf(var + 1e-5f);
        ssc[0] = scale;
        ssc[1] = beta[o] - mean * scale;
    }
    __syncthreads();
    float scale = ssc[0], shift = ssc[1];

    const float* x = side ? right : left;
    const f32x4* yp = (const f32x4*)(yB + (((size_t)(side * 2 + b) * 64 + o) << 12));
    const f32x4* xp = (const f32x4*)(x + (((size_t)b * 64 + o) << 12));
    f32x4* op = (f32x4*)(d_out + (size_t)side * (BATCH * CCH * HWD)
                         + (((size_t)b * 64 + o) << 12));

    #pragma unroll
    for (int i = 0; i < 4; ++i) {
        int idx = tid + i * 256;
        f32x4 yv = yp[idx];
        f32x4 xv = xp[idx];
        f32x4 ov;
        ov[0] = xv[0] + yv[0] * scale + shift;
        ov[1] = xv[1] + yv[1] * scale + shift;
        ov[2] = xv[2] + yv[2] * scale + shift;
        ov[3] = xv[3] + yv[3] * scale + shift;
        op[idx] = ov;
    }
}

extern "C" void kernel_launch(void* const* d_in, const int* in_sizes, int n_in,
                              void* d_out, int out_size, void* d_ws, size_t ws_size,
                              hipStream_t stream)
{
    const float* left    = (const float*)d_in[0];
    const float* right   = (const float*)d_in[1];
    const float* pre_l   = (const float*)d_in[2];
    const float* pre_r   = (const float*)d_in[3];
    const float* query_l = (const float*)d_in[4];
    const float* key_l   = (const float*)d_in[5];
    const float* query_r = (const float*)d_in[6];
    const float* key_r   = (const float*)d_in[7];
    const float* w_theta = (const float*)d_in[8];
    const float* b_theta = (const float*)d_in[9];
    const float* w_phi   = (const float*)d_in[10];
    const float* b_phi   = (const float*)d_in[11];
    const float* w_g     = (const float*)d_in[12];
    const float* b_g     = (const float*)d_in[13];
    const float* w_up    = (const float*)d_in[14];
    const float* b_up    = (const float*)d_in[15];
    const float* gamma   = (const float*)d_in[16];
    const float* beta    = (const float*)d_in[17];

    char* ws = (char*)d_ws;
    ushort* thetaB  = (ushort*)ws;                       // 1,048,576
    ushort* phiB    = (ushort*)(ws + 1048576);           // 1,048,576
    ushort* gT2     = (ushort*)(ws + 2097152);           // 1,114,112
    float*  yB      = (float*)(ws + 3211264);            // 4,194,304
    float*  part    = (float*)(ws + 7405568);            // 262,144  (ends 7,667,712)

    prep_kernel<<<192, 256, 0, stream>>>(left, right, pre_l, pre_r,
                                         query_l, key_l, query_r, key_r,
                                         w_theta, b_theta, w_phi, b_phi,
                                         w_g, b_g, thetaB, phiB, gT2);
    attn_kernel<<<512, 512, 0, stream>>>(thetaB, phiB, gT2, w_up, b_up,
                                         yB, part, (float*)d_out);
    apply_kernel<<<256, 256, 0, stream>>>(left, right, yB, part,
                                          gamma, beta, (float*)d_out);
}